// Round 4
// baseline (113.632 us; speedup 1.0000x reference)
//
#include <hip/hip_runtime.h>

#define IMGS 32
#define H 512
#define W 512
#define NPIX (H * W)            // 262144
#define NTHR 256
#define RB 16                   // rows per band
#define NBANDS (H / RB)         // 32 bands per image
#define C4W (W / 4)             // 128 float4 per row
#define NBLK (IMGS * NBANDS)    // 1024 blocks

// Combined 9-pt stencil (sum_j 2^j/15 = 1 collapses the 4 directional LTPE
// kernels + recombination into one stencil):
// s = 0.5*g - 0.25*(c0(L+R)+c1(UR+DL)+c2(U+D)+c3(UL+DR)) + 0.5
__device__ __forceinline__ float sten(float C, float L, float R, float U, float D,
                                      float UL, float UR, float DL, float DR) {
    const float c0 = 1.0f / 15.0f, c1 = 2.0f / 15.0f;
    const float c2 = 4.0f / 15.0f, c3 = 8.0f / 15.0f;
    const float acc = c0 * (L + R) + c1 * (UR + DL) + c2 * (U + D) + c3 * (UL + DR);
    return fmaf(-0.25f, acc, fmaf(0.5f, C, 0.5f));
}

union PackF2 { float2 f; unsigned long long u; };

// One-pass fused kernel. 512x16 band per block; s stays in registers across a
// per-image release/acquire sync (partials -> counter -> stats).
// Capacity: LDS 36.9 KB -> 4 blocks/CU -> all 1024 blocks co-resident.
__global__ __launch_bounds__(NTHR, 4) void ltpe_onepass(
    const float* __restrict__ x, float* __restrict__ out,
    unsigned long long* __restrict__ stats,      // [IMGS], packed (mean,rstd), 0 = not ready
    int* __restrict__ counters,                  // [IMGS]
    unsigned long long* __restrict__ partials)   // [NBLK], packed (sum,sumsq)
{
    __shared__ float G[RB + 2][W];   // 18 x 512 x 4B = 36 KB gray halo band
    __shared__ float red[8];
    __shared__ int fin;
    __shared__ float sstat[2];

    const int tid  = threadIdx.x;
    const int blk  = blockIdx.x;
    const int img  = blk >> 5;              // / NBANDS
    const int band = blk & (NBANDS - 1);
    const int r0   = band * RB;

    const float* xbase = x + (size_t)img * 3 * NPIX;

    // ---- stage gray halo rows r0-1 .. r0+16 (zero outside image) ----
#pragma unroll
    for (int it = 0; it < (RB + 2) * C4W / NTHR; ++it) {   // 9 iterations
        const int idx = it * NTHR + tid;                   // 0..2303
        const int ri  = idx >> 7;                          // 0..17
        const int c4  = idx & (C4W - 1);
        const int gr  = r0 - 1 + ri;
        float4 g4 = make_float4(0.f, 0.f, 0.f, 0.f);
        if ((unsigned)gr < (unsigned)H) {
            const float* p = xbase + gr * W + c4 * 4;
            const float4 r = *(const float4*)p;
            const float4 g = *(const float4*)(p + NPIX);
            const float4 b = *(const float4*)(p + 2 * NPIX);
            g4.x = fmaf(0.3f, r.x, fmaf(0.59f, g.x, 0.11f * b.x));
            g4.y = fmaf(0.3f, r.y, fmaf(0.59f, g.y, 0.11f * b.y));
            g4.z = fmaf(0.3f, r.z, fmaf(0.59f, g.z, 0.11f * b.z));
            g4.w = fmaf(0.3f, r.w, fmaf(0.59f, g.w, 0.11f * b.w));
        }
        *(float4*)&G[ri][c4 * 4] = g4;
    }
    __syncthreads();

    // ---- compute: thread = (half, c4); 8 rows per thread, rolling rows ----
    const int c4   = tid & (C4W - 1);
    const int half = tid >> 7;                 // 0..1
    const int lr0  = half * (RB / 2);          // first "above" LDS row

    float4 sreg[RB / 2];
    float sum = 0.0f, sq = 0.0f;

    float4 a4 = *(const float4*)&G[lr0][c4 * 4];
    float4 b4 = *(const float4*)&G[lr0 + 1][c4 * 4];
    float aL = (c4 == 0) ? 0.0f : G[lr0][c4 * 4 - 1];
    float aR = (c4 == C4W - 1) ? 0.0f : G[lr0][c4 * 4 + 4];
    float bL = (c4 == 0) ? 0.0f : G[lr0 + 1][c4 * 4 - 1];
    float bR = (c4 == C4W - 1) ? 0.0f : G[lr0 + 1][c4 * 4 + 4];

#pragma unroll
    for (int k = 0; k < RB / 2; ++k) {
        const int lr = lr0 + k + 2;            // row below
        const float4 d4 = *(const float4*)&G[lr][c4 * 4];
        const float dL = (c4 == 0) ? 0.0f : G[lr][c4 * 4 - 1];
        const float dR = (c4 == C4W - 1) ? 0.0f : G[lr][c4 * 4 + 4];

        float4 o;
        o.x = sten(b4.x, bL,   b4.y, a4.x, d4.x, aL,   a4.y, dL,   d4.y);
        o.y = sten(b4.y, b4.x, b4.z, a4.y, d4.y, a4.x, a4.z, d4.x, d4.z);
        o.z = sten(b4.z, b4.y, b4.w, a4.z, d4.z, a4.y, a4.w, d4.y, d4.w);
        o.w = sten(b4.w, b4.z, bR,   a4.w, d4.w, a4.z, aR,   d4.z, dR);
        sreg[k] = o;

        sum += (o.x + o.y) + (o.z + o.w);
        sq = fmaf(o.x, o.x, sq); sq = fmaf(o.y, o.y, sq);
        sq = fmaf(o.z, o.z, sq); sq = fmaf(o.w, o.w, sq);

        a4 = b4; aL = bL; aR = bR;
        b4 = d4; bL = dL; bR = dR;
    }

    // ---- block reduction of (sum, sq) ----
#pragma unroll
    for (int off = 32; off > 0; off >>= 1) {
        sum += __shfl_down(sum, off);
        sq  += __shfl_down(sq, off);
    }
    const int wave = tid >> 6;
    const int lane = tid & 63;
    if (lane == 0) { red[wave] = sum; red[4 + wave] = sq; }
    __syncthreads();

    // ---- publish partial, count arrivals, maybe finalize stats ----
    if (tid == 0) {
        PackF2 p;
        p.f = make_float2((red[0] + red[1]) + (red[2] + red[3]),
                          (red[4] + red[5]) + (red[6] + red[7]));
        __hip_atomic_store(&partials[blk], p.u, __ATOMIC_RELEASE,
                           __HIP_MEMORY_SCOPE_AGENT);
        const int old = __hip_atomic_fetch_add(&counters[img], 1,
                                               __ATOMIC_ACQ_REL,
                                               __HIP_MEMORY_SCOPE_AGENT);
        fin = (old == NBANDS - 1);
    }
    __syncthreads();

    if (fin && tid < 64) {
        float S1 = 0.0f, S2 = 0.0f;
        if (tid < NBANDS) {
            PackF2 p;
            p.u = __hip_atomic_load(&partials[img * NBANDS + tid],
                                    __ATOMIC_ACQUIRE, __HIP_MEMORY_SCOPE_AGENT);
            S1 = p.f.x; S2 = p.f.y;
        }
#pragma unroll
        for (int off = 32; off > 0; off >>= 1) {
            S1 += __shfl_down(S1, off);
            S2 += __shfl_down(S2, off);
        }
        if (tid == 0) {
            const float m = S1 * (1.0f / NPIX);
            const float v = S2 * (1.0f / NPIX) - m * m;
            PackF2 st;
            st.f = make_float2(m, rsqrtf(v + 1e-5f));
            __hip_atomic_store(&stats[img], st.u, __ATOMIC_RELEASE,
                               __HIP_MEMORY_SCOPE_AGENT);
        }
    }

    // ---- wait for this image's stats (finalizer sees it immediately) ----
    if (tid == 0) {
        PackF2 st;
        for (;;) {
            st.u = __hip_atomic_load(&stats[img], __ATOMIC_ACQUIRE,
                                     __HIP_MEMORY_SCOPE_AGENT);
            if (st.u != 0ULL) break;
            __builtin_amdgcn_s_sleep(2);
        }
        sstat[0] = st.f.x;
        sstat[1] = st.f.y;
    }
    __syncthreads();
    const float mean = sstat[0];
    const float rstd = sstat[1];

    // ---- normalize register-resident s, write 3 identical channels ----
    float* obase = out + (size_t)img * 3 * NPIX;
#pragma unroll
    for (int k = 0; k < RB / 2; ++k) {
        float4 o = sreg[k];
        o.x = (o.x - mean) * rstd;
        o.y = (o.y - mean) * rstd;
        o.z = (o.z - mean) * rstd;
        o.w = (o.w - mean) * rstd;
        const size_t off = (size_t)(r0 + half * (RB / 2) + k) * W + c4 * 4;
        *(float4*)(obase + off) = o;
        *(float4*)(obase + NPIX + off) = o;
        *(float4*)(obase + 2 * NPIX + off) = o;
    }
}

extern "C" void kernel_launch(void* const* d_in, const int* in_sizes, int n_in,
                              void* d_out, int out_size, void* d_ws, size_t ws_size,
                              hipStream_t stream) {
    const float* x = (const float*)d_in[0];
    float* out = (float*)d_out;

    // ws layout: [stats ull x32 | counters int x32 (+pad to 512B) | partials ull x1024]
    unsigned long long* stats = (unsigned long long*)d_ws;                 // 256 B
    int* counters = (int*)((char*)d_ws + 256);                             // 128 B
    unsigned long long* partials = (unsigned long long*)((char*)d_ws + 512); // 8 KiB

    // Re-arm sentinels every call (graph-capturable, deterministic replays).
    hipMemsetAsync(d_ws, 0, 512, stream);

    ltpe_onepass<<<dim3(NBLK), dim3(NTHR), 0, stream>>>(
        x, out, stats, counters, partials);
}

// Round 6
// 57.587 us; speedup vs baseline: 1.9732x; 1.9732x over previous
//
#include <hip/hip_runtime.h>

#define IMGS 32
#define H 512
#define W 512
#define NPIX (H * W)            // 262144
#define NTHR 256
#define RB 8                    // rows per band
#define NBANDS (H / RB)         // 64 bands per image
#define C4W (W / 4)             // 128 float4 per row
#define NBLK (IMGS * NBANDS)    // 2048 blocks

typedef float vfloat4 __attribute__((ext_vector_type(4)));  // clang vector for nt-store

// Combined 9-pt stencil (sum_j 2^j/15 = 1 collapses the 4 directional LTPE
// kernels + recombination into one stencil):
// s = 0.5*g - 0.25*(c0(L+R)+c1(UR+DL)+c2(U+D)+c3(UL+DR)) + 0.5
__device__ __forceinline__ float sten(float C, float L, float R, float U, float D,
                                      float UL, float UR, float DL, float DR) {
    const float c0 = 1.0f / 15.0f, c1 = 2.0f / 15.0f;
    const float c2 = 4.0f / 15.0f, c3 = 8.0f / 15.0f;
    const float acc = c0 * (L + R) + c1 * (UR + DL) + c2 * (U + D) + c3 * (UL + DR);
    return fmaf(-0.25f, acc, fmaf(0.5f, C, 0.5f));
}

// Stage 10 gray halo rows (r0-1 .. r0+8) into G via coalesced float4 loads.
__device__ __forceinline__ void stage_gray(const float* __restrict__ xbase,
                                           int r0, int tid, float G[RB + 2][W]) {
#pragma unroll
    for (int it = 0; it < (RB + 2) * C4W / NTHR; ++it) {   // 5 iterations
        const int idx = it * NTHR + tid;                   // 0..1279
        const int ri  = idx >> 7;                          // 0..9
        const int c4  = idx & (C4W - 1);
        const int gr  = r0 - 1 + ri;
        float4 g4 = make_float4(0.f, 0.f, 0.f, 0.f);
        if ((unsigned)gr < (unsigned)H) {
            const float* p = xbase + gr * W + c4 * 4;
            const float4 r = *(const float4*)p;
            const float4 g = *(const float4*)(p + NPIX);
            const float4 b = *(const float4*)(p + 2 * NPIX);
            g4.x = fmaf(0.3f, r.x, fmaf(0.59f, g.x, 0.11f * b.x));
            g4.y = fmaf(0.3f, r.y, fmaf(0.59f, g.y, 0.11f * b.y));
            g4.z = fmaf(0.3f, r.z, fmaf(0.59f, g.z, 0.11f * b.z));
            g4.w = fmaf(0.3f, r.w, fmaf(0.59f, g.w, 0.11f * b.w));
        }
        *(float4*)&G[ri][c4 * 4] = g4;
    }
}

// K1: stats-only pass. 512x8 band per block (grid = 2048). Reads x, computes
// gray + stencil, accumulates (sum, sumsq), writes ONE float2 per block.
__global__ __launch_bounds__(NTHR) void k1_stats(
    const float* __restrict__ x, float2* __restrict__ partials)
{
    __shared__ float G[RB + 2][W];       // 10 x 512 x 4B = 20 KB
    __shared__ float red[8];

    const int tid  = threadIdx.x;
    const int blk  = blockIdx.x;
    const int img  = blk >> 6;           // / NBANDS
    const int band = blk & (NBANDS - 1);
    const int r0   = band * RB;

    stage_gray(x + (size_t)img * 3 * NPIX, r0, tid, G);
    __syncthreads();

    const int c4   = tid & (C4W - 1);
    const int half = tid >> 7;
    const int lr0  = half * (RB / 2);

    float sum = 0.0f, sq = 0.0f;

    float4 a4 = *(const float4*)&G[lr0][c4 * 4];
    float4 b4 = *(const float4*)&G[lr0 + 1][c4 * 4];
    float aL = (c4 == 0) ? 0.0f : G[lr0][c4 * 4 - 1];
    float aR = (c4 == C4W - 1) ? 0.0f : G[lr0][c4 * 4 + 4];
    float bL = (c4 == 0) ? 0.0f : G[lr0 + 1][c4 * 4 - 1];
    float bR = (c4 == C4W - 1) ? 0.0f : G[lr0 + 1][c4 * 4 + 4];

#pragma unroll
    for (int k = 0; k < RB / 2; ++k) {
        const int lr = lr0 + k + 2;
        const float4 d4 = *(const float4*)&G[lr][c4 * 4];
        const float dL = (c4 == 0) ? 0.0f : G[lr][c4 * 4 - 1];
        const float dR = (c4 == C4W - 1) ? 0.0f : G[lr][c4 * 4 + 4];

        float4 o;
        o.x = sten(b4.x, bL,   b4.y, a4.x, d4.x, aL,   a4.y, dL,   d4.y);
        o.y = sten(b4.y, b4.x, b4.z, a4.y, d4.y, a4.x, a4.z, d4.x, d4.z);
        o.z = sten(b4.z, b4.y, b4.w, a4.z, d4.z, a4.y, a4.w, d4.y, d4.w);
        o.w = sten(b4.w, b4.z, bR,   a4.w, d4.w, a4.z, aR,   d4.z, dR);

        sum += (o.x + o.y) + (o.z + o.w);
        sq = fmaf(o.x, o.x, sq); sq = fmaf(o.y, o.y, sq);
        sq = fmaf(o.z, o.z, sq); sq = fmaf(o.w, o.w, sq);

        a4 = b4; aL = bL; aR = bR;
        b4 = d4; bL = dL; bR = dR;
    }

#pragma unroll
    for (int off = 32; off > 0; off >>= 1) {
        sum += __shfl_down(sum, off);
        sq  += __shfl_down(sq, off);
    }
    const int wave = tid >> 6;
    const int lane = tid & 63;
    if (lane == 0) { red[wave] = sum; red[4 + wave] = sq; }
    __syncthreads();
    if (tid == 0) {
        partials[blk] = make_float2((red[0] + red[1]) + (red[2] + red[3]),
                                    (red[4] + red[5]) + (red[6] + red[7]));
    }
}

// K2: per-image stats from the 64 band partials (block-redundant, L2-resident),
// recompute stencil from x (L2/L3-warm after K1), normalize, nt-store 3
// channels. Band order group-reversed so K2's early blocks hit the x tiles K1
// read last, on the same XCD (b%8 preserved).
__global__ __launch_bounds__(NTHR) void k2_norm(
    const float* __restrict__ x, const float2* __restrict__ partials,
    float* __restrict__ out)
{
    __shared__ float G[RB + 2][W];
    __shared__ float sm[2];

    const int tid = threadIdx.x;
    const int b   = blockIdx.x;
    const int g   = b >> 3;                      // 256 groups of 8
    const int blk = (((NBLK / 8 - 1) - g) << 3) | (b & 7);   // reversed, XCD kept
    const int img  = blk >> 6;
    const int band = blk & (NBANDS - 1);
    const int r0   = band * RB;

    // ---- per-image stats (one wave, 64 partials) ----
    if (tid < 64) {
        const float2 p = partials[img * NBANDS + tid];
        float S1 = p.x, S2 = p.y;
#pragma unroll
        for (int off = 32; off > 0; off >>= 1) {
            S1 += __shfl_down(S1, off);
            S2 += __shfl_down(S2, off);
        }
        if (tid == 0) {
            const float m = S1 * (1.0f / NPIX);
            const float v = S2 * (1.0f / NPIX) - m * m;
            sm[0] = m;
            sm[1] = rsqrtf(v + 1e-5f);
        }
    }

    stage_gray(x + (size_t)img * 3 * NPIX, r0, tid, G);
    __syncthreads();

    const float mean = sm[0];
    const float rstd = sm[1];

    const int c4   = tid & (C4W - 1);
    const int half = tid >> 7;
    const int lr0  = half * (RB / 2);

    float* obase = out + (size_t)img * 3 * NPIX;

    float4 a4 = *(const float4*)&G[lr0][c4 * 4];
    float4 b4 = *(const float4*)&G[lr0 + 1][c4 * 4];
    float aL = (c4 == 0) ? 0.0f : G[lr0][c4 * 4 - 1];
    float aR = (c4 == C4W - 1) ? 0.0f : G[lr0][c4 * 4 + 4];
    float bL = (c4 == 0) ? 0.0f : G[lr0 + 1][c4 * 4 - 1];
    float bR = (c4 == C4W - 1) ? 0.0f : G[lr0 + 1][c4 * 4 + 4];

#pragma unroll
    for (int k = 0; k < RB / 2; ++k) {
        const int lr = lr0 + k + 2;
        const float4 d4 = *(const float4*)&G[lr][c4 * 4];
        const float dL = (c4 == 0) ? 0.0f : G[lr][c4 * 4 - 1];
        const float dR = (c4 == C4W - 1) ? 0.0f : G[lr][c4 * 4 + 4];

        float4 o;
        o.x = sten(b4.x, bL,   b4.y, a4.x, d4.x, aL,   a4.y, dL,   d4.y);
        o.y = sten(b4.y, b4.x, b4.z, a4.y, d4.y, a4.x, a4.z, d4.x, d4.z);
        o.z = sten(b4.z, b4.y, b4.w, a4.z, d4.z, a4.y, a4.w, d4.y, d4.w);
        o.w = sten(b4.w, b4.z, bR,   a4.w, d4.w, a4.z, aR,   d4.z, dR);

        vfloat4 v;
        v.x = (o.x - mean) * rstd;
        v.y = (o.y - mean) * rstd;
        v.z = (o.z - mean) * rstd;
        v.w = (o.w - mean) * rstd;

        const size_t off = (size_t)(r0 + half * (RB / 2) + k) * W + c4 * 4;
        __builtin_nontemporal_store(v, (vfloat4*)(obase + off));
        __builtin_nontemporal_store(v, (vfloat4*)(obase + NPIX + off));
        __builtin_nontemporal_store(v, (vfloat4*)(obase + 2 * NPIX + off));

        a4 = b4; aL = bL; aR = bR;
        b4 = d4; bL = dL; bR = dR;
    }
}

extern "C" void kernel_launch(void* const* d_in, const int* in_sizes, int n_in,
                              void* d_out, int out_size, void* d_ws, size_t ws_size,
                              hipStream_t stream) {
    const float* x = (const float*)d_in[0];
    float* out = (float*)d_out;
    float2* partials = (float2*)d_ws;   // 2048 * 8 B = 16 KiB, fully rewritten by K1

    k1_stats<<<dim3(NBLK), dim3(NTHR), 0, stream>>>(x, partials);
    k2_norm<<<dim3(NBLK), dim3(NTHR), 0, stream>>>(x, partials, out);
}